// Round 11
// baseline (326.859 us; speedup 1.0000x reference)
//
#include <hip/hip_runtime.h>

typedef unsigned short USHORT;
typedef short short8 __attribute__((ext_vector_type(8)));
typedef float f32x4 __attribute__((ext_vector_type(4)));

__device__ __forceinline__ float fast_sig(float x) {
  return __builtin_amdgcn_rcpf(1.f + __builtin_amdgcn_exp2f(x * -1.442695041f));
}
__device__ __forceinline__ USHORT f2b(float f) {   // fp32 -> bf16 RNE
  unsigned int u = __float_as_uint(f);
  unsigned int r = (u + 0x7fffu + ((u >> 16) & 1u)) >> 16;
  return (USHORT)r;
}

// =====================================================================
// K0a: repack conv weights -> coalesced A-frag layout (VALIDATED R9).
// =====================================================================
__global__ __launch_bounds__(256) void prep_w_k(
    const float* __restrict__ cw, USHORT* __restrict__ wrep) {
  const int idx = blockIdx.x * 256 + threadIdx.x;   // (co,ci,t9)
  const int t9 = idx % 9;
  const int r  = idx / 9;
  const int ci = r & 127;
  const int co = r >> 7;
  const int c  = ci >> 5;
  const int kg = (ci >> 3) & 3;
  const int j  = ci & 7;
  const int st = co >> 4;
  const int mm = co & 15;
  wrep[((c * 9 + t9) * 8 + st) * 512 + (kg * 16 + mm) * 8 + j] = f2b(cw[idx]);
}

// =====================================================================
// K0m: mamba weights -> bf16 (+ fp32 A2 table) in d_ws (validated region).
// mw: win[64][16]@0, xpw[48][32]@1024 (rows 33..47 zero), wout[16][32]@2560,
// A2 fp32[32][16] @ ushort 3072 (byte 6144).  3584 threads.
// =====================================================================
__global__ __launch_bounds__(256) void prep_mw_k(
    const float* __restrict__ w_in, const float* __restrict__ xpw,
    const float* __restrict__ wout, const float* __restrict__ alog,
    USHORT* __restrict__ mw) {
  const int t = blockIdx.x * 256 + threadIdx.x;
  if (t < 1024) {
    mw[t] = f2b(w_in[t]);
  } else if (t < 2560) {
    const int i = t - 1024;
    const int j = i >> 5, d = i & 31;
    mw[t] = (j < 33) ? f2b(xpw[j * 32 + d]) : (USHORT)0;
  } else if (t < 3072) {
    mw[t] = f2b(wout[t - 2560]);
  } else if (t < 3584) {
    const int i = t - 3072;
    ((float*)(mw + 3072))[i] = -__expf(alog[i]) * 1.442695041f;
  }
}

// =====================================================================
// K0b: transpose x -> x_t[b][h][w][ci] bf16 (VALIDATED).
// =====================================================================
__global__ __launch_bounds__(256) void x2t_k(
    const float* __restrict__ x, USHORT* __restrict__ xt_g) {
  __shared__ USHORT lt[128 * 18];
  const int tid = threadIdx.x;
  const int bid = blockIdx.x;
  const int cqi = bid & 7;
  const int h   = (bid >> 3) & 127;
  const int b   = bid >> 10;
  const int ci0 = cqi * 16;

#pragma unroll
  for (int it = 0; it < 2; ++it) {
    int task = it * 256 + tid;
    int ci = task >> 5;
    int wq = task & 31;
    float4 v = ((const float4*)(x + ((size_t)((b * 128 + ci0 + ci) * 128 + h)) * 128))[wq];
    lt[(wq * 4 + 0) * 18 + ci] = f2b(v.x);
    lt[(wq * 4 + 1) * 18 + ci] = f2b(v.y);
    lt[(wq * 4 + 2) * 18 + ci] = f2b(v.z);
    lt[(wq * 4 + 3) * 18 + ci] = f2b(v.w);
  }
  __syncthreads();
  unsigned int* dst = (unsigned int*)xt_g + ((size_t)((b * 128 + h) * 128)) * 64 + cqi * 8;
#pragma unroll
  for (int it = 0; it < 4; ++it) {
    int task = it * 256 + tid;
    int w = task >> 3;
    int p = task & 7;
    dst[(size_t)w * 64 + p] = *(const unsigned int*)&lt[w * 18 + 2 * p];
  }
}

// =====================================================================
// K1: 3x3 conv implicit-GEMM MFMA (R9-validated structure) with weights
// staged per 32-ci chunk into LDS (73.7 KB) -- A-frags become ds_read_b128
// instead of per-wave global re-fetch (604 MB -> 151 MB L2 traffic).
// grid 512 = wh(2)*h(128)*b(2); block 512 (8 waves); LDS 132.5 KB.
// Epilogue: y stored bf16 (identical values to R10's in-mamba conversion).
// =====================================================================
__global__ __launch_bounds__(512) void conv_mfma_k(
    const USHORT* __restrict__ xt_g, const USHORT* __restrict__ wrep,
    const float* __restrict__ cb, USHORT* __restrict__ yb) {
  __shared__ USHORT xt[3 * 72 * 136];   // 58752 B
  __shared__ USHORT wl[36864];          // 73728 B: one 32-ci weight chunk

  const int tid = threadIdx.x;
  const int bid = blockIdx.x;
  const int wh  = bid & 1;
  const int h   = (bid >> 1) & 127;
  const int b   = bid >> 8;
  const int w0  = wh * 64;

  const int wv   = tid >> 6;
  const int lane = tid & 63;
  const int m    = lane & 15;
  const int kg   = lane >> 4;
  const int ch2  = wv & 1;
  const int ws0  = (wv >> 1) * 16;

  // ---- stage x_t[b, h-1..h+1, w0-4..w0+67, ci] (VALIDATED) ----
  for (int it = 0; it < 7; ++it) {
    int task = it * 512 + tid;
    if (task < 3456) {
      int dh  = task / 1152;
      int rem = task - dh * 1152;
      int wl2 = rem >> 4;
      int cq  = task & 15;
      int wg  = w0 - 4 + wl2;
      int hh  = h + dh - 1;
      uint4 v = make_uint4(0u, 0u, 0u, 0u);
      if (((unsigned)wg < 128u) && ((unsigned)hh < 128u))
        v = *(const uint4*)(xt_g + ((size_t)((b * 128 + hh) * 128 + wg)) * 128 + cq * 8);
      *(uint4*)&xt[(dh * 72 + wl2) * 136 + cq * 8] = v;
    }
  }

  f32x4 acc[4];
#pragma unroll
  for (int s = 0; s < 4; ++s) acc[s] = (f32x4){0.f, 0.f, 0.f, 0.f};

  for (int c = 0; c < 4; ++c) {
    __syncthreads();   // c=0: xt staged; c>0: prior wl reads complete
    // stage this chunk's weights: 4608 uint4, 9 per thread
    {
      const uint4* src = (const uint4*)wrep + c * 4608;
      uint4* dst = (uint4*)wl;
#pragma unroll
      for (int i = 0; i < 9; ++i)
        dst[i * 512 + tid] = src[i * 512 + tid];
    }
    __syncthreads();
#pragma unroll
    for (int t9 = 0; t9 < 9; ++t9) {
      const int kh = t9 / 3, kw = t9 - kh * 3;
      short8 a[4];
#pragma unroll
      for (int s = 0; s < 4; ++s)
        a[s] = *(const short8*)&wl[(t9 * 8 + ch2 * 4 + s) * 512 + lane * 8];
      short8 bf = *(const short8*)&xt[(kh * 72 + ws0 + m + kw + 3) * 136 + c * 32 + kg * 8];
#pragma unroll
      for (int s = 0; s < 4; ++s)
        acc[s] = __builtin_amdgcn_mfma_f32_16x16x32_bf16(a[s], bf, acc[s], 0, 0, 0);
    }
  }

  const int w = w0 + ws0 + m;
#pragma unroll
  for (int s = 0; s < 4; ++s) {
#pragma unroll
    for (int r = 0; r < 4; ++r) {
      const int co = ch2 * 64 + s * 16 + kg * 4 + r;
      yb[((size_t)((b * 128 + co) * 128 + h)) * 128 + w] = f2b(acc[s][r] + cb[co]);
    }
  }
}

// =====================================================================
// K2: Mamba — R10-VALIDATED structure; weights from prepacked mw
// (no in-register pack8), y read directly as bf16 from global,
// A2 table precomputed fp32. Scan = validated per-element exp2 form.
// =====================================================================
__global__ __launch_bounds__(256) void mamba_k(
    const USHORT* __restrict__ yb,
    const USHORT* __restrict__ mw,    // win@0, xpw@1024, wout@2560, A2f32@3072
    const float* __restrict__ c1w, const float* __restrict__ c1b,
    const float* __restrict__ dtw, const float* __restrict__ dtb,
    const float* __restrict__ dvec,
    float* __restrict__ m, float* __restrict__ stats) {
  __shared__ float xzal[4352];          // in_proj out [64 e][68]; aliased after:
  float* xz  = xzal;
  float* Bs  = xzal;                    // [64 tok][16]
  float* Cs  = xzal + 1024;             // [64 tok][16]
  float* dts = xzal + 2048;             // [64 tok]
  __shared__ USHORT xcs[64 * 40];       // [tok][ch pad40] bf16
  __shared__ USHORT yms[64 * 40];
  __shared__ float reds[8];

  const int tid  = threadIdx.x;
  const int wv   = tid >> 6;
  const int lane = tid & 63;
  const int nm   = lane & 15;
  const int quad = lane >> 4;
  const int s    = tid >> 5;
  const int ch   = tid & 31;
  const size_t blk = (size_t)blockIdx.x;
  const float* A2f = (const float*)(mw + 3072);

  // ---- in_proj: K=16 padded to 32 (quads 2,3 zero); y read from global ----
  {
    short8 af = (short8){0, 0, 0, 0, 0, 0, 0, 0};
    if (quad < 2)
      af = *(const short8*)(yb + blk * 1024 + (wv * 16 + nm) * 16 + quad * 8);
#pragma unroll
    for (int nt = 0; nt < 4; ++nt) {
      short8 bw = (short8){0, 0, 0, 0, 0, 0, 0, 0};
      if (quad < 2)
        bw = *(const short8*)(mw + (nt * 16 + nm) * 16 + quad * 8);
      f32x4 cc = (f32x4){0.f, 0.f, 0.f, 0.f};
      cc = __builtin_amdgcn_mfma_f32_16x16x32_bf16(af, bw, cc, 0, 0, 0);
      *(f32x4*)&xz[(nt * 16 + nm) * 68 + wv * 16 + quad * 4] = cc;
    }
  }
  __syncthreads();

  // ---- conv1d(k=4, causal) + SiLU (VALIDATED) ----
  float xc[8], zs[8];
  {
    const float4 cwv = *(const float4*)(c1w + ch * 4);
    const float cbr = c1b[ch];
    float4 xa = *(float4*)&xz[ch * 68 + s * 8];
    float4 xb = *(float4*)&xz[ch * 68 + s * 8 + 4];
    float4 za = *(float4*)&xz[(ch + 32) * 68 + s * 8];
    float4 zb = *(float4*)&xz[(ch + 32) * 68 + s * 8 + 4];
    float xi[8] = {xa.x, xa.y, xa.z, xa.w, xb.x, xb.y, xb.z, xb.w};
    float zv[8] = {za.x, za.y, za.z, za.w, zb.x, zb.y, zb.z, zb.w};
#pragma unroll
    for (int l = 0; l < 8; ++l) {
      float a = fmaf(cwv.w, xi[l], cbr);
      if (l >= 1) a = fmaf(cwv.z, xi[l - 1], a);
      if (l >= 2) a = fmaf(cwv.y, xi[l - 2], a);
      if (l >= 3) a = fmaf(cwv.x, xi[l - 3], a);
      float sc = a * fast_sig(a);
      xc[l] = sc;
      xcs[(s * 8 + l) * 40 + ch] = f2b(sc);
      zs[l] = zv[l] * fast_sig(zv[l]);
    }
  }
  __syncthreads();

  // ---- x_proj: scatter dt/B/C (VALIDATED) ----
  {
    short8 axf = *(const short8*)&xcs[(wv * 16 + nm) * 40 + quad * 8];
    const int tok0 = wv * 16 + quad * 4;
#pragma unroll
    for (int nt = 0; nt < 3; ++nt) {
      short8 bw = *(const short8*)(mw + 1024 + (nt * 16 + nm) * 32 + quad * 8);
      f32x4 cc = (f32x4){0.f, 0.f, 0.f, 0.f};
      cc = __builtin_amdgcn_mfma_f32_16x16x32_bf16(axf, bw, cc, 0, 0, 0);
      if (nt == 0) {
        if (nm == 0) {
          *(f32x4*)&dts[tok0] = cc;
        } else {
#pragma unroll
          for (int r = 0; r < 4; ++r) Bs[(tok0 + r) * 16 + nm - 1] = cc[r];
        }
      } else if (nt == 1) {
        if (nm == 0) {
#pragma unroll
          for (int r = 0; r < 4; ++r) Bs[(tok0 + r) * 16 + 15] = cc[r];
        } else {
#pragma unroll
          for (int r = 0; r < 4; ++r) Cs[(tok0 + r) * 16 + nm - 1] = cc[r];
        }
      } else {
        if (nm == 0) {
#pragma unroll
          for (int r = 0; r < 4; ++r) Cs[(tok0 + r) * 16 + 15] = cc[r];
        }
      }
    }
  }
  __syncthreads();

  // ---- selective scan: VALIDATED per-element exp2 form, A2 from table ----
  {
    const float dwv = dtw[ch], dbv = dtb[ch], Dv = dvec[ch];
    float A2r[16];
#pragma unroll
    for (int q = 0; q < 4; ++q) {
      float4 av = ((const float4*)(A2f + ch * 16))[q];
      A2r[q * 4 + 0] = av.x; A2r[q * 4 + 1] = av.y;
      A2r[q * 4 + 2] = av.z; A2r[q * 4 + 3] = av.w;
    }
    float hreg[16];
#pragma unroll
    for (int st = 0; st < 16; ++st) hreg[st] = 0.f;
#pragma unroll
    for (int l = 0; l < 8; ++l) {
      const int tok = s * 8 + l;
      float pre = fmaf(dts[tok], dwv, dbv);
      float t = __builtin_amdgcn_exp2f(pre * 1.442695041f);
      float dtl = 0.6931471806f * __builtin_amdgcn_logf(1.f + t);
      dtl = (pre > 20.f) ? pre : dtl;
      float dtxc = dtl * xc[l];
      float yl = 0.f;
#pragma unroll
      for (int q = 0; q < 4; ++q) {
        float4 bv = *(const float4*)&Bs[tok * 16 + q * 4];
        float4 cv = *(const float4*)&Cs[tok * 16 + q * 4];
        float aa;
        aa = __builtin_amdgcn_exp2f(dtl * A2r[q * 4 + 0]);
        hreg[q * 4 + 0] = fmaf(aa, hreg[q * 4 + 0], dtxc * bv.x);
        yl = fmaf(hreg[q * 4 + 0], cv.x, yl);
        aa = __builtin_amdgcn_exp2f(dtl * A2r[q * 4 + 1]);
        hreg[q * 4 + 1] = fmaf(aa, hreg[q * 4 + 1], dtxc * bv.y);
        yl = fmaf(hreg[q * 4 + 1], cv.y, yl);
        aa = __builtin_amdgcn_exp2f(dtl * A2r[q * 4 + 2]);
        hreg[q * 4 + 2] = fmaf(aa, hreg[q * 4 + 2], dtxc * bv.z);
        yl = fmaf(hreg[q * 4 + 2], cv.z, yl);
        aa = __builtin_amdgcn_exp2f(dtl * A2r[q * 4 + 3]);
        hreg[q * 4 + 3] = fmaf(aa, hreg[q * 4 + 3], dtxc * bv.w);
        yl = fmaf(hreg[q * 4 + 3], cv.w, yl);
      }
      yms[tok * 40 + ch] = f2b(fmaf(Dv, xc[l], yl) * zs[l]);
    }
  }
  __syncthreads();

  // ---- out_proj + GN stats (VALIDATED) ----
  {
    short8 ayf = *(const short8*)&yms[(wv * 16 + nm) * 40 + quad * 8];
    short8 bwf = *(const short8*)(mw + 2560 + nm * 32 + quad * 8);
    f32x4 cc = (f32x4){0.f, 0.f, 0.f, 0.f};
    cc = __builtin_amdgcn_mfma_f32_16x16x32_bf16(ayf, bwf, cc, 0, 0, 0);
    const int tok0 = wv * 16 + quad * 4;
    float ls = 0.f, lq = 0.f;
#pragma unroll
    for (int r = 0; r < 4; ++r) {
      const int tok = tok0 + r;
      const int sq = tok >> 3, l = tok & 7;
      m[(blk * 8 + sq) * 128 + l * 16 + nm] = cc[r];
      ls += cc[r];
      lq = fmaf(cc[r], cc[r], lq);
    }
#pragma unroll
    for (int off = 32; off > 0; off >>= 1) {
      ls += __shfl_down(ls, off);
      lq += __shfl_down(lq, off);
    }
    if (lane == 0) { reds[wv * 2] = ls; reds[wv * 2 + 1] = lq; }
  }
  __syncthreads();
  if (tid == 0) {
    float S = reds[0] + reds[2] + reds[4] + reds[6];
    float Q = reds[1] + reds[3] + reds[5] + reds[7];
    int n0 = blockIdx.x * 8;
    int bb = n0 >> 14;
    int cc2 = (n0 >> 7) & 127;
    int gg = cc2 >> 5;
    atomicAdd(&stats[(bb * 4 + gg) * 2 + 0], S);
    atomicAdd(&stats[(bb * 4 + gg) * 2 + 1], Q);
  }
}

// =====================================================================
// K3: GroupNorm finalize + SiLU + residual, in-place on d_out (VALIDATED).
// =====================================================================
__global__ __launch_bounds__(256) void gn_silu_k(
    const float* __restrict__ x,
    const float* __restrict__ gnw, const float* __restrict__ gnb,
    const float* __restrict__ stats, float* __restrict__ out) {
  const int idx0 = (blockIdx.x * 256 + threadIdx.x) * 4;
  const int bb = idx0 >> 21;
  const int cc = (idx0 >> 14) & 127;
  const int gg = cc >> 5;
  const float S = stats[(bb * 4 + gg) * 2 + 0];
  const float Q = stats[(bb * 4 + gg) * 2 + 1];
  const float inv  = 1.0f / 524288.0f;
  const float mu   = S * inv;
  const float var  = fmaf(Q, inv, -mu * mu);
  const float rstd = rsqrtf(var + 1e-5f);
  const float gw  = gnw[cc] * rstd;
  const float gb2 = gnb[cc] - mu * gw;

  float4 mv = *(const float4*)(out + idx0);
  float4 xv = *(const float4*)(x + idx0);
  float mvv[4] = { mv.x, mv.y, mv.z, mv.w };
  float xf[4]  = { xv.x, xv.y, xv.z, xv.w };
  float res[4];
#pragma unroll
  for (int j = 0; j < 4; ++j) {
    float nv = fmaf(mvv[j], gw, gb2);
    float sv = nv * fast_sig(nv);
    res[j] = xf[j] + sv;
  }
  *(float4*)(out + idx0) = make_float4(res[0], res[1], res[2], res[3]);
}

// =====================================================================
extern "C" void kernel_launch(void* const* d_in, const int* in_sizes, int n_in,
                              void* d_out, int out_size, void* d_ws, size_t ws_size,
                              hipStream_t stream) {
  const float* x     = (const float*)d_in[0];
  const float* convw = (const float*)d_in[1];
  const float* convb = (const float*)d_in[2];
  const float* gnw   = (const float*)d_in[3];
  const float* gnb   = (const float*)d_in[4];
  const float* winp  = (const float*)d_in[5];
  const float* c1w   = (const float*)d_in[6];
  const float* c1b   = (const float*)d_in[7];
  const float* xpw   = (const float*)d_in[8];
  const float* dtw   = (const float*)d_in[9];
  const float* dtb   = (const float*)d_in[10];
  const float* alog  = (const float*)d_in[11];
  const float* dvec  = (const float*)d_in[12];
  const float* wout  = (const float*)d_in[13];

  // d_ws (>=32MB proven by R2's PASS): yb bf16 8MB | stats @16MB | mw @16MB+64
  USHORT* yb    = (USHORT*)d_ws;
  float*  stats = (float*)((char*)d_ws + 16777216);
  USHORT* mw    = (USHORT*)((char*)d_ws + 16777216 + 64);
  USHORT* xt_g  = (USHORT*)d_out;                     // 8 MB (dead before m)
  USHORT* wrep  = (USHORT*)d_out + 4194304;           // 288 KB
  float*  m     = (float*)d_out;

  hipMemsetAsync(stats, 0, 16 * sizeof(float), stream);
  hipLaunchKernelGGL(prep_w_k, dim3(576), dim3(256), 0, stream, convw, wrep);
  hipLaunchKernelGGL(prep_mw_k, dim3(14), dim3(256), 0, stream, winp, xpw, wout, alog, mw);
  hipLaunchKernelGGL(x2t_k, dim3(2048), dim3(256), 0, stream, x, xt_g);
  hipLaunchKernelGGL(conv_mfma_k, dim3(512), dim3(512), 0, stream, xt_g, wrep, convb, yb);
  hipLaunchKernelGGL(mamba_k, dim3(4096), dim3(256), 0, stream,
                     yb, mw, c1w, c1b, dtw, dtb, dvec, m, stats);
  hipLaunchKernelGGL(gn_silu_k, dim3(4096), dim3(256), 0, stream,
                     x, gnw, gnb, stats, (float*)d_out);
}